// Round 4
// baseline (192.906 us; speedup 1.0000x reference)
//
#include <hip/hip_runtime.h>

// loss = sum_all (out-tgt)^2 / (H*W*B),  B=64,H=W=256, weight=1
//
// Single-kernel threadfence reduction:
//   2048 blocks x 256 threads (exactly 8 blocks/CU, 256/XCD), each thread
//   exactly 34 float4 pairs, nontemporal loads, wave64 shuffle reduce ->
//   LDS -> partial[block]; last-arriving block (device-scope atomic counter)
//   folds all partials in fixed order + tail, scales, writes d_out[0].
//   Counter zeroed per call via 4-byte hipMemsetAsync (graph-capturable).

#define THREADS 256

using f4 = __attribute__((ext_vector_type(4))) float;  // nontemporal-compatible

__device__ __forceinline__ float block_reduce(float acc, float* wsum) {
    #pragma unroll
    for (int off = 32; off >= 1; off >>= 1)
        acc += __shfl_down(acc, off, 64);
    int lane = threadIdx.x & 63;
    int wid = threadIdx.x >> 6;
    if (lane == 0) wsum[wid] = acc;
    __syncthreads();
    float s = 0.0f;
    if (threadIdx.x == 0) {
        #pragma unroll
        for (int w = 0; w < THREADS / 64; ++w) s += wsum[w];
    }
    return s;  // valid in thread 0 only
}

__global__ __launch_bounds__(THREADS) void mse_kernel(
    const f4* __restrict__ a4, const f4* __restrict__ b4,
    const float* __restrict__ a, const float* __restrict__ b,
    float* __restrict__ partial, unsigned int* __restrict__ counter,
    int per_thread, int tail_start, int n,
    float* __restrict__ out, float scale) {
    __shared__ float wsum[THREADS / 64];
    __shared__ int is_last;

    int base = blockIdx.x * (THREADS * per_thread) + threadIdx.x;

    float acc = 0.0f;
    #pragma unroll 8
    for (int k = 0; k < per_thread; ++k) {
        f4 x = __builtin_nontemporal_load(&a4[base + k * THREADS]);
        f4 y = __builtin_nontemporal_load(&b4[base + k * THREADS]);
        f4 d = x - y;
        acc = fmaf(d.x, d.x, acc);
        acc = fmaf(d.y, d.y, acc);
        acc = fmaf(d.z, d.z, acc);
        acc = fmaf(d.w, d.w, acc);
    }

    float s = block_reduce(acc, wsum);

    // publish partial, then count arrival (device scope)
    if (threadIdx.x == 0) {
        partial[blockIdx.x] = s;
        __threadfence();
        unsigned int old = atomicAdd(counter, 1u);
        is_last = (old == gridDim.x - 1) ? 1 : 0;
    }
    __syncthreads();

    if (is_last) {
        __threadfence();  // acquire: make all partials visible
        float facc = 0.0f;
        for (int i = threadIdx.x; i < (int)gridDim.x; i += THREADS)
            facc += partial[i];
        for (int i = tail_start + threadIdx.x; i < n; i += THREADS) {
            float d = a[i] - b[i];
            facc = fmaf(d, d, facc);
        }
        __syncthreads();  // wsum reuse
        float fs = block_reduce(facc, wsum);
        if (threadIdx.x == 0) out[0] = fs * scale;
    }
}

extern "C" void kernel_launch(void* const* d_in, const int* in_sizes, int n_in,
                              void* d_out, int out_size, void* d_ws, size_t ws_size,
                              hipStream_t stream) {
    const float* a = (const float*)d_in[0];   // output [64,17,256,256] f32
    const float* b = (const float*)d_in[1];   // target [64,17,256,256] f32
    float* out = (float*)d_out;

    float* partial = (float*)d_ws;                         // blocks floats
    unsigned int* counter = (unsigned int*)((char*)d_ws + (64 * 1024));

    int n = in_sizes[0];                      // 71,303,168
    int n4 = n >> 2;                          // 17,825,792 float4 pairs
    const int blocks = 2048;                  // 8/CU, 256/XCD exactly
    int per_thread = n4 / (blocks * THREADS); // 34 for this shape
    int tail_start = blocks * THREADS * per_thread * 4;  // == n here (no tail)

    const float scale = 1.0f / (256.0f * 256.0f * 64.0f);

    hipMemsetAsync(counter, 0, sizeof(unsigned int), stream);
    mse_kernel<<<blocks, THREADS, 0, stream>>>(
        (const f4*)a, (const f4*)b, a, b, partial, counter,
        per_thread, tail_start, n, out, scale);
}

// Round 5
// 91.509 us; speedup vs baseline: 2.1081x; 2.1081x over previous
//
#include <hip/hip_runtime.h>

// loss = sum_all (out-tgt)^2 / (H*W*B),  B=64,H=W=256, weight=1
//
// Two-pass deterministic reduction (R3 structure, load-balanced grid):
//   Pass 1: 2048 blocks x 256 threads (exactly 8 blocks/CU), each thread
//           exactly 34 float4 pairs (compile-time), nontemporal loads,
//           unroll 8, two accumulators, wave64 shuffle reduce -> LDS ->
//           partial[block] in d_ws.
//   Pass 2: 1 block folds partials (+ generic tail), scales, writes d_out.

#define THREADS 256
#define PER_THREAD 34   // float4 per thread in pass 1 (compile-time!)

using f4 = __attribute__((ext_vector_type(4))) float;  // nontemporal-compatible

__global__ __launch_bounds__(THREADS) void mse_partial_kernel(
    const f4* __restrict__ a4, const f4* __restrict__ b4,
    float* __restrict__ partial) {
    int base = blockIdx.x * (THREADS * PER_THREAD) + threadIdx.x;

    float acc0 = 0.0f, acc1 = 0.0f;
    #pragma unroll 8
    for (int k = 0; k < PER_THREAD; ++k) {
        f4 x = __builtin_nontemporal_load(&a4[base + k * THREADS]);
        f4 y = __builtin_nontemporal_load(&b4[base + k * THREADS]);
        f4 d = x - y;
        acc0 = fmaf(d.x, d.x, acc0);
        acc1 = fmaf(d.y, d.y, acc1);
        acc0 = fmaf(d.z, d.z, acc0);
        acc1 = fmaf(d.w, d.w, acc1);
    }
    float acc = acc0 + acc1;

    // wave64 butterfly reduce
    #pragma unroll
    for (int off = 32; off >= 1; off >>= 1)
        acc += __shfl_down(acc, off, 64);

    __shared__ float wsum[THREADS / 64];
    int lane = threadIdx.x & 63;
    int wid = threadIdx.x >> 6;
    if (lane == 0) wsum[wid] = acc;
    __syncthreads();

    if (threadIdx.x == 0) {
        float s = 0.0f;
        #pragma unroll
        for (int w = 0; w < THREADS / 64; ++w) s += wsum[w];
        partial[blockIdx.x] = s;
    }
}

// Folds per-block partials AND any tail elements [tail_start, n) not covered
// by pass 1 (tail is 0 for the benchmark shape; kept for generality).
__global__ __launch_bounds__(THREADS) void mse_final_kernel(
    const float* __restrict__ partial, int nb,
    const float* __restrict__ a, const float* __restrict__ b,
    int tail_start, int n,
    float* __restrict__ out, float scale) {
    float acc = 0.0f;
    for (int i = threadIdx.x; i < nb; i += THREADS) acc += partial[i];
    for (int i = tail_start + threadIdx.x; i < n; i += THREADS) {
        float d = a[i] - b[i];
        acc = fmaf(d, d, acc);
    }

    #pragma unroll
    for (int off = 32; off >= 1; off >>= 1)
        acc += __shfl_down(acc, off, 64);

    __shared__ float wsum[THREADS / 64];
    int lane = threadIdx.x & 63;
    int wid = threadIdx.x >> 6;
    if (lane == 0) wsum[wid] = acc;
    __syncthreads();

    if (threadIdx.x == 0) {
        float s = 0.0f;
        #pragma unroll
        for (int w = 0; w < THREADS / 64; ++w) s += wsum[w];
        out[0] = s * scale;
    }
}

extern "C" void kernel_launch(void* const* d_in, const int* in_sizes, int n_in,
                              void* d_out, int out_size, void* d_ws, size_t ws_size,
                              hipStream_t stream) {
    const float* a = (const float*)d_in[0];   // output [64,17,256,256] f32
    const float* b = (const float*)d_in[1];   // target [64,17,256,256] f32
    float* out = (float*)d_out;
    float* partial = (float*)d_ws;

    int n = in_sizes[0];                      // 71,303,168
    int n4 = n >> 2;                          // 17,825,792 = 2048*256*34 exactly
    int per_block = THREADS * PER_THREAD;     // 8704 float4 per block
    int blocks = n4 / per_block;              // 2048 (exactly 8 blocks/CU)
    int tail_start = blocks * per_block * 4;  // == n here (no tail)

    const float scale = 1.0f / (256.0f * 256.0f * 64.0f);

    mse_partial_kernel<<<blocks, THREADS, 0, stream>>>(
        (const f4*)a, (const f4*)b, partial);
    mse_final_kernel<<<1, THREADS, 0, stream>>>(
        partial, blocks, a, b, tail_start, n, out, scale);
}

// Round 7
// 90.869 us; speedup vs baseline: 2.1229x; 1.0070x over previous
//
#include <hip/hip_runtime.h>

// loss = sum_all (out-tgt)^2 / (H*W*B),  B=64,H=W=256, weight=1
//
// Two-pass deterministic reduction (R3 grid config, hand-pipelined loads):
//   Pass 1: 2176 blocks x 256 threads, each thread 32 float4 pairs in 8
//           batches of 4; batch k+1's 8 nontemporal loads issue before
//           batch k's FMAs (software pipeline, all indices compile-time).
//   Pass 2: 1 block folds partials (+ generic tail), scales, writes d_out.

#define THREADS 256
#define PER_THREAD 32          // float4 per thread in pass 1
#define BATCH 4                // float4 pairs per pipeline stage
#define NBATCH (PER_THREAD / BATCH)

using f4 = __attribute__((ext_vector_type(4))) float;  // nontemporal-compatible

__global__ __launch_bounds__(THREADS) void mse_partial_kernel(
    const f4* __restrict__ a4, const f4* __restrict__ b4,
    float* __restrict__ partial) {
    int base = blockIdx.x * (THREADS * PER_THREAD) + threadIdx.x;

    float acc0 = 0.0f, acc1 = 0.0f;
    f4 xa[BATCH], xb[BATCH];

    // prologue: batch 0 in flight
    #pragma unroll
    for (int j = 0; j < BATCH; ++j) {
        xa[j] = __builtin_nontemporal_load(&a4[base + j * THREADS]);
        xb[j] = __builtin_nontemporal_load(&b4[base + j * THREADS]);
    }

    #pragma unroll
    for (int k = 0; k < NBATCH; ++k) {
        f4 ya[BATCH], yb[BATCH];
        if (k + 1 < NBATCH) {
            #pragma unroll
            for (int j = 0; j < BATCH; ++j) {
                ya[j] = __builtin_nontemporal_load(&a4[base + ((k + 1) * BATCH + j) * THREADS]);
                yb[j] = __builtin_nontemporal_load(&b4[base + ((k + 1) * BATCH + j) * THREADS]);
            }
        }
        #pragma unroll
        for (int j = 0; j < BATCH; ++j) {
            f4 d = xa[j] - xb[j];
            acc0 = fmaf(d.x, d.x, acc0);
            acc1 = fmaf(d.y, d.y, acc1);
            acc0 = fmaf(d.z, d.z, acc0);
            acc1 = fmaf(d.w, d.w, acc1);
        }
        if (k + 1 < NBATCH) {
            #pragma unroll
            for (int j = 0; j < BATCH; ++j) { xa[j] = ya[j]; xb[j] = yb[j]; }
        }
    }
    float acc = acc0 + acc1;

    // wave64 butterfly reduce
    #pragma unroll
    for (int off = 32; off >= 1; off >>= 1)
        acc += __shfl_down(acc, off, 64);

    __shared__ float wsum[THREADS / 64];
    int lane = threadIdx.x & 63;
    int wid = threadIdx.x >> 6;
    if (lane == 0) wsum[wid] = acc;
    __syncthreads();

    if (threadIdx.x == 0) {
        float s = 0.0f;
        #pragma unroll
        for (int w = 0; w < THREADS / 64; ++w) s += wsum[w];
        partial[blockIdx.x] = s;
    }
}

// Folds per-block partials AND any tail elements [tail_start, n) not covered
// by pass 1 (tail is 0 for the benchmark shape; kept for generality).
__global__ __launch_bounds__(THREADS) void mse_final_kernel(
    const float* __restrict__ partial, int nb,
    const float* __restrict__ a, const float* __restrict__ b,
    int tail_start, int n,
    float* __restrict__ out, float scale) {
    float acc = 0.0f;
    for (int i = threadIdx.x; i < nb; i += THREADS) acc += partial[i];
    for (int i = tail_start + threadIdx.x; i < n; i += THREADS) {
        float d = a[i] - b[i];
        acc = fmaf(d, d, acc);
    }

    #pragma unroll
    for (int off = 32; off >= 1; off >>= 1)
        acc += __shfl_down(acc, off, 64);

    __shared__ float wsum[THREADS / 64];
    int lane = threadIdx.x & 63;
    int wid = threadIdx.x >> 6;
    if (lane == 0) wsum[wid] = acc;
    __syncthreads();

    if (threadIdx.x == 0) {
        float s = 0.0f;
        #pragma unroll
        for (int w = 0; w < THREADS / 64; ++w) s += wsum[w];
        out[0] = s * scale;
    }
}

extern "C" void kernel_launch(void* const* d_in, const int* in_sizes, int n_in,
                              void* d_out, int out_size, void* d_ws, size_t ws_size,
                              hipStream_t stream) {
    const float* a = (const float*)d_in[0];   // output [64,17,256,256] f32
    const float* b = (const float*)d_in[1];   // target [64,17,256,256] f32
    float* out = (float*)d_out;
    float* partial = (float*)d_ws;

    int n = in_sizes[0];                      // 71,303,168
    int n4 = n >> 2;                          // 17,825,792 float4 pairs
    int per_block = THREADS * PER_THREAD;     // 8192 float4 per block
    int blocks = n4 / per_block;              // 2176 (exact for this shape)
    int tail_start = blocks * per_block * 4;  // == n here (no tail)

    const float scale = 1.0f / (256.0f * 256.0f * 64.0f);

    mse_partial_kernel<<<blocks, THREADS, 0, stream>>>(
        (const f4*)a, (const f4*)b, partial);
    mse_final_kernel<<<1, THREADS, 0, stream>>>(
        partial, blocks, a, b, tail_start, n, out, scale);
}